// Round 1
// baseline (809.714 us; speedup 1.0000x reference)
//
#include <hip/hip_runtime.h>
#include <hip/hip_bf16.h>
#include <cstdint>

typedef __attribute__((ext_vector_type(4))) float f32x4;
typedef __attribute__((ext_vector_type(8))) short s16x8;

#define MAXDEG 256

__device__ inline unsigned short f2bf(float f) {
    unsigned u = __float_as_uint(f);
    u = (u + 0x7fffu + ((u >> 16) & 1u)) >> 16;   // round-to-nearest-even
    return (unsigned short)u;
}
__device__ inline float bf_lo(unsigned x) { return __uint_as_float(x << 16); }
__device__ inline float bf_hi(unsigned x) { return __uint_as_float(x & 0xffff0000u); }

// ---------------- W (f32) -> bf16 ----------------
__global__ void convW(const float* __restrict__ W, unsigned short* __restrict__ Wb) {
    int i = blockIdx.x * 256 + threadIdx.x;
    if (i < 256 * 256) Wb[i] = f2bf(W[i]);
}

// ---------------- h = X @ W^T + b, stored bf16 ----------------
// block = 256 threads = 4 waves. Block tile: 32 nodes x 256 outs.
// Wave w covers outs [w*64, w*64+64) as 4 n-tiles of 16; 2 m-tiles of 16 nodes.
__global__ __launch_bounds__(256) void gemm_h(
    const float* __restrict__ X, const unsigned short* __restrict__ Wb,
    const float* __restrict__ bvec, unsigned short* __restrict__ Hb) {
    const int lane = threadIdx.x & 63;
    const int wave = threadIdx.x >> 6;
    const int l15 = lane & 15, quad = lane >> 4;
    const int nbase = blockIdx.x * 32;
    const int obase = wave * 64;

    f32x4 acc[2][4] = {};
    for (int k = 0; k < 256; k += 32) {
        s16x8 afr[2];
#pragma unroll
        for (int mt = 0; mt < 2; ++mt) {
            const float* ap = X + (size_t)(nbase + mt * 16 + l15) * 256 + k + quad * 8;
            f32x4 x0 = *(const f32x4*)ap;
            f32x4 x1 = *(const f32x4*)(ap + 4);
            s16x8 a;
            a[0] = (short)f2bf(x0.x); a[1] = (short)f2bf(x0.y);
            a[2] = (short)f2bf(x0.z); a[3] = (short)f2bf(x0.w);
            a[4] = (short)f2bf(x1.x); a[5] = (short)f2bf(x1.y);
            a[6] = (short)f2bf(x1.z); a[7] = (short)f2bf(x1.w);
            afr[mt] = a;
        }
#pragma unroll
        for (int t = 0; t < 4; ++t) {
            s16x8 bfr = *(const s16x8*)(Wb + (size_t)(obase + t * 16 + l15) * 256 + k + quad * 8);
            acc[0][t] = __builtin_amdgcn_mfma_f32_16x16x32_bf16(afr[0], bfr, acc[0][t], 0, 0, 0);
            acc[1][t] = __builtin_amdgcn_mfma_f32_16x16x32_bf16(afr[1], bfr, acc[1][t], 0, 0, 0);
        }
    }
#pragma unroll
    for (int t = 0; t < 4; ++t) {
        int o = obase + t * 16 + l15;
        float bv = bvec[o];
#pragma unroll
        for (int mt = 0; mt < 2; ++mt) {
#pragma unroll
            for (int r = 0; r < 4; ++r) {
                int node = nbase + mt * 16 + quad * 4 + r;
                Hb[(size_t)node * 256 + o] = f2bf(acc[mt][t][r] + bv);
            }
        }
    }
}

// ---------------- a1/a2 per-node scalar scores ----------------
// block = 256 = 4 waves, one node per wave; lane covers 4 of 256 dims.
__global__ __launch_bounds__(256) void a_scores(
    const unsigned short* __restrict__ Hb,
    const float* __restrict__ wa1, const float* __restrict__ ba1,
    const float* __restrict__ wa2, const float* __restrict__ ba2,
    float* __restrict__ a1, float* __restrict__ a2) {
    const int lane = threadIdx.x & 63;
    const int wave = threadIdx.x >> 6;
    const int node = blockIdx.x * 4 + wave;
    uint2 hv = *(const uint2*)(Hb + (size_t)node * 256 + lane * 4);
    float x0 = bf_lo(hv.x), x1 = bf_hi(hv.x), x2 = bf_lo(hv.y), x3 = bf_hi(hv.y);
    f32x4 w1 = *(const f32x4*)(wa1 + lane * 4);
    f32x4 w2 = *(const f32x4*)(wa2 + lane * 4);
    float s1 = x0 * w1.x + x1 * w1.y + x2 * w1.z + x3 * w1.w;
    float s2 = x0 * w2.x + x1 * w2.y + x2 * w2.z + x3 * w2.w;
#pragma unroll
    for (int o = 32; o; o >>= 1) {
        s1 += __shfl_xor(s1, o);
        s2 += __shfl_xor(s2, o);
    }
    if (lane == 0) {
        a1[node] = s1 + ba1[0];
        a2[node] = s2 + ba2[0];
    }
}

// ---------------- CSR build ----------------
__global__ void hist_k(const int* __restrict__ rows, int* __restrict__ cnt, int e) {
    int i = blockIdx.x * 256 + threadIdx.x;
    if (i < e) atomicAdd(&cnt[rows[i]], 1);
}

// scan1: per-block (2048 elems) inclusive scan of cnt -> off[1+i]; block total -> bsum
__global__ __launch_bounds__(256) void scan1(
    const int* __restrict__ cnt, int* __restrict__ off, int* __restrict__ bsum, int n) {
    __shared__ int lds[256];
    const int tid = threadIdx.x;
    const int base = blockIdx.x * 2048 + tid * 8;
    int v[8];
    int run = 0;
#pragma unroll
    for (int j = 0; j < 8; ++j) {
        int idx = base + j;
        int x = (idx < n) ? cnt[idx] : 0;
        run += x;
        v[j] = run;
    }
    lds[tid] = run;
    __syncthreads();
#pragma unroll
    for (int ofs = 1; ofs < 256; ofs <<= 1) {
        int t = (tid >= ofs) ? lds[tid - ofs] : 0;
        __syncthreads();
        lds[tid] += t;
        __syncthreads();
    }
    int pre = lds[tid] - run;
#pragma unroll
    for (int j = 0; j < 8; ++j) {
        int idx = base + j;
        if (idx < n) off[1 + idx] = v[j] + pre;
    }
    if (tid == 255) bsum[blockIdx.x] = lds[255];
}

__global__ void scan2(int* __restrict__ bsum, int* __restrict__ off, int nb) {
    if (threadIdx.x == 0 && blockIdx.x == 0) {
        int run = 0;
        for (int i = 0; i < nb; ++i) {
            int t = bsum[i];
            bsum[i] = run;
            run += t;
        }
        off[0] = 0;
    }
}

__global__ __launch_bounds__(256) void scan3(
    const int* __restrict__ bsum, int* __restrict__ off, int n) {
    int add = bsum[blockIdx.x];
    int base = blockIdx.x * 2048 + threadIdx.x * 8;
#pragma unroll
    for (int j = 0; j < 8; ++j) {
        int idx = base + j;
        if (idx < n) off[1 + idx] += add;
    }
}

__global__ void scatter_k(const int* __restrict__ rows, const int* __restrict__ colsIn,
                          const int* __restrict__ off, int* __restrict__ cur,
                          int* __restrict__ colsOut, int e) {
    int i = blockIdx.x * 256 + threadIdx.x;
    if (i < e) {
        int r = rows[i];
        int p = off[r] + atomicAdd(&cur[r], 1);
        colsOut[p] = colsIn[i];
    }
}

// ---------------- softmax + weighted aggregation ----------------
// block = 256 = 4 waves, one node per wave. Lane covers 4 of 256 dims.
__global__ __launch_bounds__(256) void aggregate(
    const int* __restrict__ off, const int* __restrict__ cols,
    const float* __restrict__ a1, const float* __restrict__ a2,
    const unsigned short* __restrict__ Hb, float* __restrict__ out) {
    __shared__ float s_ev[4][MAXDEG];
    __shared__ int s_col[4][MAXDEG];
    const int lane = threadIdx.x & 63;
    const int wave = threadIdx.x >> 6;
    const int node = blockIdx.x * 4 + wave;
    const int o0 = off[node];
    const int deg = off[node + 1] - o0;
    const float a1n = a1[node];

    // pass 1: scores -> exp, LDS stash, denominator
    float s = 0.0f;
    for (int i = lane; i < deg; i += 64) {
        int c = cols[o0 + i];
        float v = a1n + a2[c];
        v = (v > 0.0f) ? v : 0.01f * v;
        float ev = __expf(v);
        if (i < MAXDEG) {
            s_ev[wave][i] = ev;
            s_col[wave][i] = c;
        }
        s += ev;
    }
#pragma unroll
    for (int o = 32; o; o >>= 1) s += __shfl_xor(s, o);
    float inv = (s > 0.0f) ? 1.0f / s : 0.0f;
    __syncthreads();

    // pass 2: out[node] = sum att * h[col]
    f32x4 acc = {0.0f, 0.0f, 0.0f, 0.0f};
    const int cbase = lane * 4;
    const int nfast = (deg < MAXDEG) ? deg : MAXDEG;
    for (int i = 0; i < nfast; ++i) {
        float w = s_ev[wave][i] * inv;
        int c = s_col[wave][i];
        uint2 hv = *(const uint2*)(Hb + (size_t)c * 256 + cbase);
        acc.x += w * bf_lo(hv.x);
        acc.y += w * bf_hi(hv.x);
        acc.z += w * bf_lo(hv.y);
        acc.w += w * bf_hi(hv.y);
    }
    for (int i = MAXDEG; i < deg; ++i) {  // rare overflow path
        int c = cols[o0 + i];
        float v = a1n + a2[c];
        v = (v > 0.0f) ? v : 0.01f * v;
        float w = __expf(v) * inv;
        uint2 hv = *(const uint2*)(Hb + (size_t)c * 256 + cbase);
        acc.x += w * bf_lo(hv.x);
        acc.y += w * bf_hi(hv.x);
        acc.z += w * bf_lo(hv.y);
        acc.w += w * bf_hi(hv.y);
    }
    *(f32x4*)(out + (size_t)node * 256 + cbase) = acc;
}

extern "C" void kernel_launch(void* const* d_in, const int* in_sizes, int n_in,
                              void* d_out, int out_size, void* d_ws, size_t ws_size,
                              hipStream_t stream) {
    const float* X   = (const float*)d_in[0];
    const int*   idx = (const int*)d_in[1];
    const float* W   = (const float*)d_in[2];
    const float* b   = (const float*)d_in[3];
    const float* wa1 = (const float*)d_in[4];
    const float* ba1 = (const float*)d_in[5];
    const float* wa2 = (const float*)d_in[6];
    const float* ba2 = (const float*)d_in[7];
    float* out = (float*)d_out;

    const int n = in_sizes[0] / 256;  // 100000
    const int e = in_sizes[1] / 2;    // 3200000

    char* p = (char*)d_ws;
    auto alloc = [&](size_t bytes) -> char* {
        char* r = p;
        p += (bytes + 255) & ~(size_t)255;
        return r;
    };
    unsigned short* Hb = (unsigned short*)alloc((size_t)n * 256 * 2);
    unsigned short* Wb = (unsigned short*)alloc(256 * 256 * 2);
    float* a1  = (float*)alloc((size_t)n * 4);
    float* a2  = (float*)alloc((size_t)n * 4);
    int* cnt   = (int*)alloc((size_t)n * 4);
    int* off   = (int*)alloc((size_t)(n + 1) * 4);
    int* cur   = (int*)alloc((size_t)n * 4);
    int* bsum  = (int*)alloc(256 * 4);
    int* colS  = (int*)alloc((size_t)e * 4);

    const int* rows   = idx;
    const int* colsIn = idx + e;

    hipMemsetAsync(cnt, 0, (size_t)n * 4, stream);
    hipMemsetAsync(cur, 0, (size_t)n * 4, stream);

    convW<<<256, 256, 0, stream>>>(W, Wb);
    gemm_h<<<n / 32, 256, 0, stream>>>(X, Wb, b, Hb);
    a_scores<<<n / 4, 256, 0, stream>>>(Hb, wa1, ba1, wa2, ba2, a1, a2);
    hist_k<<<(e + 255) / 256, 256, 0, stream>>>(rows, cnt, e);
    int nb = (n + 2047) / 2048;
    scan1<<<nb, 256, 0, stream>>>(cnt, off, bsum, n);
    scan2<<<1, 64, 0, stream>>>(bsum, off, nb);
    scan3<<<nb, 256, 0, stream>>>(bsum, off, n);
    scatter_k<<<(e + 255) / 256, 256, 0, stream>>>(rows, colsIn, off, cur, colS, e);
    aggregate<<<n / 4, 256, 0, stream>>>(off, colS, a1, a2, Hb, out);
}

// Round 2
// 736.753 us; speedup vs baseline: 1.0990x; 1.0990x over previous
//
#include <hip/hip_runtime.h>
#include <hip/hip_bf16.h>
#include <cstdint>

typedef __attribute__((ext_vector_type(4))) float f32x4;
typedef __attribute__((ext_vector_type(8))) short s16x8;

#define MAXDEG 256

__device__ inline unsigned short f2bf(float f) {
    unsigned u = __float_as_uint(f);
    u = (u + 0x7fffu + ((u >> 16) & 1u)) >> 16;   // round-to-nearest-even
    return (unsigned short)u;
}
__device__ inline float bf_lo(unsigned x) { return __uint_as_float(x << 16); }
__device__ inline float bf_hi(unsigned x) { return __uint_as_float(x & 0xffff0000u); }

// ---------------- W (f32) -> bf16 ----------------
__global__ void convW(const float* __restrict__ W, unsigned short* __restrict__ Wb) {
    int i = blockIdx.x * 256 + threadIdx.x;
    if (i < 256 * 256) Wb[i] = f2bf(W[i]);
}

// ---------------- X (f32) -> bf16, 8 elems/thread ----------------
__global__ __launch_bounds__(256) void convX(const float* __restrict__ X,
                                             unsigned short* __restrict__ Xb) {
    size_t i = ((size_t)blockIdx.x * 256 + threadIdx.x) * 8;
    f32x4 x0 = *(const f32x4*)(X + i);
    f32x4 x1 = *(const f32x4*)(X + i + 4);
    s16x8 r;
    r[0] = (short)f2bf(x0.x); r[1] = (short)f2bf(x0.y);
    r[2] = (short)f2bf(x0.z); r[3] = (short)f2bf(x0.w);
    r[4] = (short)f2bf(x1.x); r[5] = (short)f2bf(x1.y);
    r[6] = (short)f2bf(x1.z); r[7] = (short)f2bf(x1.w);
    *(s16x8*)(Xb + i) = r;
}

// ---------------- h = X @ W^T + b, stored bf16 (bf16 inputs) ----------------
// block = 256 threads = 4 waves. Block tile: 32 nodes x 256 outs.
// Wave w covers outs [w*64, w*64+64); 2 m-tiles of 16 nodes.
__global__ __launch_bounds__(256) void gemm_h(
    const unsigned short* __restrict__ Xb, const unsigned short* __restrict__ Wb,
    const float* __restrict__ bvec, unsigned short* __restrict__ Hb) {
    const int lane = threadIdx.x & 63;
    const int wave = threadIdx.x >> 6;
    const int l15 = lane & 15, quad = lane >> 4;
    const int nbase = blockIdx.x * 32;
    const int obase = wave * 64;

    f32x4 acc[2][4] = {};
#pragma unroll
    for (int k = 0; k < 256; k += 32) {
        s16x8 afr[2];
#pragma unroll
        for (int mt = 0; mt < 2; ++mt)
            afr[mt] = *(const s16x8*)(Xb + (size_t)(nbase + mt * 16 + l15) * 256 + k + quad * 8);
#pragma unroll
        for (int t = 0; t < 4; ++t) {
            s16x8 bfr = *(const s16x8*)(Wb + (size_t)(obase + t * 16 + l15) * 256 + k + quad * 8);
            acc[0][t] = __builtin_amdgcn_mfma_f32_16x16x32_bf16(afr[0], bfr, acc[0][t], 0, 0, 0);
            acc[1][t] = __builtin_amdgcn_mfma_f32_16x16x32_bf16(afr[1], bfr, acc[1][t], 0, 0, 0);
        }
    }
#pragma unroll
    for (int t = 0; t < 4; ++t) {
        int o = obase + t * 16 + l15;
        float bv = bvec[o];
#pragma unroll
        for (int mt = 0; mt < 2; ++mt) {
#pragma unroll
            for (int r = 0; r < 4; ++r) {
                int node = nbase + mt * 16 + quad * 4 + r;
                Hb[(size_t)node * 256 + o] = f2bf(acc[mt][t][r] + bv);
            }
        }
    }
}

// ---------------- a1/a2 per-node scalar scores ----------------
__global__ __launch_bounds__(256) void a_scores(
    const unsigned short* __restrict__ Hb,
    const float* __restrict__ wa1, const float* __restrict__ ba1,
    const float* __restrict__ wa2, const float* __restrict__ ba2,
    float* __restrict__ a1, float* __restrict__ a2) {
    const int lane = threadIdx.x & 63;
    const int wave = threadIdx.x >> 6;
    const int node = blockIdx.x * 4 + wave;
    uint2 hv = *(const uint2*)(Hb + (size_t)node * 256 + lane * 4);
    float x0 = bf_lo(hv.x), x1 = bf_hi(hv.x), x2 = bf_lo(hv.y), x3 = bf_hi(hv.y);
    f32x4 w1 = *(const f32x4*)(wa1 + lane * 4);
    f32x4 w2 = *(const f32x4*)(wa2 + lane * 4);
    float s1 = x0 * w1.x + x1 * w1.y + x2 * w1.z + x3 * w1.w;
    float s2 = x0 * w2.x + x1 * w2.y + x2 * w2.z + x3 * w2.w;
#pragma unroll
    for (int o = 32; o; o >>= 1) {
        s1 += __shfl_xor(s1, o);
        s2 += __shfl_xor(s2, o);
    }
    if (lane == 0) {
        a1[node] = s1 + ba1[0];
        a2[node] = s2 + ba2[0];
    }
}

// ---------------- CSR build ----------------
// hist with fused rank capture: rank[i] = this edge's ordinal within its row
__global__ void hist_k(const int* __restrict__ rows, int* __restrict__ cnt,
                       int* __restrict__ rank, int e) {
    int i = blockIdx.x * 256 + threadIdx.x;
    if (i < e) rank[i] = atomicAdd(&cnt[rows[i]], 1);
}

__global__ __launch_bounds__(256) void scan1(
    const int* __restrict__ cnt, int* __restrict__ off, int* __restrict__ bsum, int n) {
    __shared__ int lds[256];
    const int tid = threadIdx.x;
    const int base = blockIdx.x * 2048 + tid * 8;
    int v[8];
    int run = 0;
#pragma unroll
    for (int j = 0; j < 8; ++j) {
        int idx = base + j;
        int x = (idx < n) ? cnt[idx] : 0;
        run += x;
        v[j] = run;
    }
    lds[tid] = run;
    __syncthreads();
#pragma unroll
    for (int ofs = 1; ofs < 256; ofs <<= 1) {
        int t = (tid >= ofs) ? lds[tid - ofs] : 0;
        __syncthreads();
        lds[tid] += t;
        __syncthreads();
    }
    int pre = lds[tid] - run;
#pragma unroll
    for (int j = 0; j < 8; ++j) {
        int idx = base + j;
        if (idx < n) off[1 + idx] = v[j] + pre;
    }
    if (tid == 255) bsum[blockIdx.x] = lds[255];
}

__global__ void scan2(int* __restrict__ bsum, int* __restrict__ off, int nb) {
    if (threadIdx.x == 0 && blockIdx.x == 0) {
        int run = 0;
        for (int i = 0; i < nb; ++i) {
            int t = bsum[i];
            bsum[i] = run;
            run += t;
        }
        off[0] = 0;
    }
}

__global__ __launch_bounds__(256) void scan3(
    const int* __restrict__ bsum, int* __restrict__ off, int n) {
    int add = bsum[blockIdx.x];
    int base = blockIdx.x * 2048 + threadIdx.x * 8;
#pragma unroll
    for (int j = 0; j < 8; ++j) {
        int idx = base + j;
        if (idx < n) off[1 + idx] += add;
    }
}

__global__ void scatter_k(const int* __restrict__ rows, const int* __restrict__ colsIn,
                          const int* __restrict__ rank, const int* __restrict__ off,
                          int* __restrict__ colsOut, int e) {
    int i = blockIdx.x * 256 + threadIdx.x;
    if (i < e) {
        int p = off[rows[i]] + rank[i];
        colsOut[p] = colsIn[i];
    }
}

// ---------------- softmax + weighted aggregation ----------------
// block = 256 = 4 waves, one node per wave. Lane covers 4 of 256 dims.
// Unrolled x4 with independent accumulators; 1/s folded into final scale.
__global__ __launch_bounds__(256) void aggregate(
    const int* __restrict__ off, const int* __restrict__ cols,
    const float* __restrict__ a1, const float* __restrict__ a2,
    const unsigned short* __restrict__ Hb, float* __restrict__ out) {
    __shared__ float s_ev[4][MAXDEG];
    __shared__ int s_col[4][MAXDEG];
    const int lane = threadIdx.x & 63;
    const int wave = threadIdx.x >> 6;
    const int node = blockIdx.x * 4 + wave;
    const int o0 = off[node];
    const int deg = off[node + 1] - o0;
    const float a1n = a1[node];

    // pass 1: scores -> exp (unnormalized), LDS stash, denominator
    float s = 0.0f;
    for (int i = lane; i < deg; i += 64) {
        int c = cols[o0 + i];
        float v = a1n + a2[c];
        v = (v > 0.0f) ? v : 0.01f * v;
        float ev = __expf(v);
        if (i < MAXDEG) {
            s_ev[wave][i] = ev;
            s_col[wave][i] = c;
        }
        s += ev;
    }
#pragma unroll
    for (int o = 32; o; o >>= 1) s += __shfl_xor(s, o);
    float inv = (s > 0.0f) ? 1.0f / s : 0.0f;
    __syncthreads();

    // pass 2: out[node] = (sum ev * h[col]) * inv
    f32x4 acc0 = {0,0,0,0}, acc1 = {0,0,0,0}, acc2 = {0,0,0,0}, acc3 = {0,0,0,0};
    const int cbase = lane * 4;
    const int nfast = (deg < MAXDEG) ? deg : MAXDEG;
    const int nf4 = nfast & ~3;
    int i = 0;
    for (; i < nf4; i += 4) {
        float w0 = s_ev[wave][i],     w1 = s_ev[wave][i + 1];
        float w2 = s_ev[wave][i + 2], w3 = s_ev[wave][i + 3];
        int c0 = s_col[wave][i],     c1 = s_col[wave][i + 1];
        int c2 = s_col[wave][i + 2], c3 = s_col[wave][i + 3];
        uint2 h0 = *(const uint2*)(Hb + (size_t)c0 * 256 + cbase);
        uint2 h1 = *(const uint2*)(Hb + (size_t)c1 * 256 + cbase);
        uint2 h2 = *(const uint2*)(Hb + (size_t)c2 * 256 + cbase);
        uint2 h3 = *(const uint2*)(Hb + (size_t)c3 * 256 + cbase);
        acc0.x += w0 * bf_lo(h0.x); acc0.y += w0 * bf_hi(h0.x);
        acc0.z += w0 * bf_lo(h0.y); acc0.w += w0 * bf_hi(h0.y);
        acc1.x += w1 * bf_lo(h1.x); acc1.y += w1 * bf_hi(h1.x);
        acc1.z += w1 * bf_lo(h1.y); acc1.w += w1 * bf_hi(h1.y);
        acc2.x += w2 * bf_lo(h2.x); acc2.y += w2 * bf_hi(h2.x);
        acc2.z += w2 * bf_lo(h2.y); acc2.w += w2 * bf_hi(h2.y);
        acc3.x += w3 * bf_lo(h3.x); acc3.y += w3 * bf_hi(h3.x);
        acc3.z += w3 * bf_lo(h3.y); acc3.w += w3 * bf_hi(h3.y);
    }
    for (; i < nfast; ++i) {
        float w = s_ev[wave][i];
        int c = s_col[wave][i];
        uint2 hv = *(const uint2*)(Hb + (size_t)c * 256 + cbase);
        acc0.x += w * bf_lo(hv.x); acc0.y += w * bf_hi(hv.x);
        acc0.z += w * bf_lo(hv.y); acc0.w += w * bf_hi(hv.y);
    }
    for (int j = MAXDEG; j < deg; ++j) {  // rare overflow path
        int c = cols[o0 + j];
        float v = a1n + a2[c];
        v = (v > 0.0f) ? v : 0.01f * v;
        float w = __expf(v);
        uint2 hv = *(const uint2*)(Hb + (size_t)c * 256 + cbase);
        acc0.x += w * bf_lo(hv.x); acc0.y += w * bf_hi(hv.x);
        acc0.z += w * bf_lo(hv.y); acc0.w += w * bf_hi(hv.y);
    }
    f32x4 acc;
    acc.x = ((acc0.x + acc1.x) + (acc2.x + acc3.x)) * inv;
    acc.y = ((acc0.y + acc1.y) + (acc2.y + acc3.y)) * inv;
    acc.z = ((acc0.z + acc1.z) + (acc2.z + acc3.z)) * inv;
    acc.w = ((acc0.w + acc1.w) + (acc2.w + acc3.w)) * inv;
    *(f32x4*)(out + (size_t)node * 256 + cbase) = acc;
}

extern "C" void kernel_launch(void* const* d_in, const int* in_sizes, int n_in,
                              void* d_out, int out_size, void* d_ws, size_t ws_size,
                              hipStream_t stream) {
    const float* X   = (const float*)d_in[0];
    const int*   idx = (const int*)d_in[1];
    const float* W   = (const float*)d_in[2];
    const float* b   = (const float*)d_in[3];
    const float* wa1 = (const float*)d_in[4];
    const float* ba1 = (const float*)d_in[5];
    const float* wa2 = (const float*)d_in[6];
    const float* ba2 = (const float*)d_in[7];
    float* out = (float*)d_out;

    const int n = in_sizes[0] / 256;  // 100000
    const int e = in_sizes[1] / 2;    // 3200000

    char* p = (char*)d_ws;
    auto alloc = [&](size_t bytes) -> char* {
        char* r = p;
        p += (bytes + 255) & ~(size_t)255;
        return r;
    };
    unsigned short* Hb = (unsigned short*)alloc((size_t)n * 256 * 2);
    unsigned short* Xb = (unsigned short*)alloc((size_t)n * 256 * 2);
    unsigned short* Wb = (unsigned short*)alloc(256 * 256 * 2);
    float* a1  = (float*)alloc((size_t)n * 4);
    float* a2  = (float*)alloc((size_t)n * 4);
    int* cnt   = (int*)alloc((size_t)n * 4);
    int* off   = (int*)alloc((size_t)(n + 1) * 4);
    int* bsum  = (int*)alloc(256 * 4);
    int* rank  = (int*)alloc((size_t)e * 4);
    int* colS  = (int*)alloc((size_t)e * 4);

    const int* rows   = idx;
    const int* colsIn = idx + e;

    hipMemsetAsync(cnt, 0, (size_t)n * 4, stream);

    convW<<<256, 256, 0, stream>>>(W, Wb);
    convX<<<(n * 256) / (256 * 8), 256, 0, stream>>>(X, Xb);
    gemm_h<<<n / 32, 256, 0, stream>>>(Xb, Wb, b, Hb);
    a_scores<<<n / 4, 256, 0, stream>>>(Hb, wa1, ba1, wa2, ba2, a1, a2);
    hist_k<<<(e + 255) / 256, 256, 0, stream>>>(rows, cnt, rank, e);
    int nb = (n + 2047) / 2048;
    scan1<<<nb, 256, 0, stream>>>(cnt, off, bsum, n);
    scan2<<<1, 64, 0, stream>>>(bsum, off, nb);
    scan3<<<nb, 256, 0, stream>>>(bsum, off, n);
    scatter_k<<<(e + 255) / 256, 256, 0, stream>>>(rows, colsIn, rank, off, colS, e);
    aggregate<<<n / 4, 256, 0, stream>>>(off, colS, a1, a2, Hb, out);
}